// Round 1
// 471.135 us; speedup vs baseline: 1.0906x; 1.0906x over previous
//
#include <hip/hip_runtime.h>
#include <hip/hip_bf16.h>
#include <math.h>

#define D_MODEL 2048
#define N_HEADS 16
#define D_HEAD  128
#define BATCH   64
#define SEQ     128
#define BT      (BATCH*SEQ)   // 8192 rows
#define LDF     6144          // fused QKV row stride
#define KOFF    2048
#define VOFF    4096

typedef __bf16 bf16;
typedef __attribute__((ext_vector_type(8))) __bf16 bf16x8;
typedef __attribute__((ext_vector_type(4))) float  f32x4;

__device__ __forceinline__ f32x4 mfma16(bf16x8 a, bf16x8 b, f32x4 c) {
    return __builtin_amdgcn_mfma_f32_16x16x32_bf16(a, b, c, 0, 0, 0);
}

__device__ __forceinline__ bf16x8 cvt8_f32(const float* p) {
    f32x4 lo = *(const f32x4*)p;
    f32x4 hi = *(const f32x4*)(p + 4);
    bf16x8 r;
    r[0] = (bf16)lo[0]; r[1] = (bf16)lo[1]; r[2] = (bf16)lo[2]; r[3] = (bf16)lo[3];
    r[4] = (bf16)hi[0]; r[5] = (bf16)hi[1]; r[6] = (bf16)hi[2]; r[7] = (bf16)hi[3];
    return r;
}

// async global->LDS, 16 B/lane; LDS dest = wave-uniform base + lane*16 (m104)
__device__ __forceinline__ void gl2lds16(const bf16* g, bf16* l) {
    __builtin_amdgcn_global_load_lds(
        (const __attribute__((address_space(1))) void*)g,
        (__attribute__((address_space(3))) void*)l, 16, 0, 0);
}

// rope 8 consecutive d-elements (4 even/odd pairs); tpos = seq position,
// pair0 = global pair index of element 0. exp/sincos in fp32.
__device__ __forceinline__ bf16x8 rope8(bf16x8 v, int tpos, int pair0) {
    bf16x8 r;
    for (int m = 0; m < 4; ++m) {
        int i = pair0 + m;
        float theta = __expf((float)(2 * i) * (-9.210340371976184f / 128.0f));
        float ang   = (float)tpos * theta;
        float sn, cs;
        __sincosf(ang, &sn, &cs);
        float e = (float)v[2 * m], o = (float)v[2 * m + 1];
        r[2 * m]     = (bf16)(e * cs - o * sn);
        r[2 * m + 1] = (bf16)(e * sn + o * cs);
    }
    return r;
}

// ---------------------------------------------------------------------------
// fp32 -> bf16 elementwise convert, 8 elems/thread
// ---------------------------------------------------------------------------
__global__ __launch_bounds__(256) void cvt_kernel(const float* __restrict__ src,
                                                  bf16* __restrict__ dst, int n8)
{
    int i = blockIdx.x * 256 + threadIdx.x;
    if (i < n8) *(bf16x8*)(dst + (size_t)i * 8) = cvt8_f32(src + (size_t)i * 8);
}

// 3 weight matrices in one launch: sel = i>>19 (n8w = 2^19 per matrix)
__global__ __launch_bounds__(256) void cvt_w3(const float* __restrict__ w0,
                                              const float* __restrict__ w1,
                                              const float* __restrict__ w2,
                                              bf16* __restrict__ dst)
{
    int i   = blockIdx.x * 256 + threadIdx.x;     // < 3*2^19
    int sel = i >> 19;
    int off = i & ((1 << 19) - 1);
    const float* s = (sel == 0) ? w0 : (sel == 1) ? w1 : w2;
    *(bf16x8*)(dst + (size_t)i * 8) = cvt8_f32(s + (size_t)off * 8);
}

// ---------------------------------------------------------------------------
// gemm256: C[M,N] = A[M,K] @ B[N,K]^T, bf16 in, OutT out.
// 256x256 tile, BK=64, 512 thr = 8 waves (2Mx4N), per-wave 128x64 output.
// 8-phase-style schedule (4 phases/K-tile, 2 K-tiles per dbuf cycle):
//   P0: ds_read A(mh0)x8 + B(j0,j1)x4 | bar | MFMA quad(0,0) | bar
//   P1: ds_read B(j2,j3)x4            | bar | MFMA quad(0,1) | bar
//   P2: ds_read A(mh1)x8              | bar | MFMA quad(1,1) | bar   <- all
//       reads of this buffer complete workgroup-wide here
//   P3: STAGE tile+2 into same buf (8 gl2lds) | bar | MFMA quad(1,0)
//       | s_waitcnt vmcnt(8)  (drains tile+1's loads, issued a full tile
//         ago; NEVER 0 in main loop) | bar
// B frags cached whole K-tile, A per-half: 24 ds_read_b128/wave/tile (min).
// LDS xor-swizzle (phys chunk = logical ^ (row&7)) via pre-swizzled global
// source (m104-safe), 0 bank conflicts measured with this pattern.
// T5 setprio around each 16-MFMA cluster; T1 chunked XCD swizzle on blockIdx.
// ---------------------------------------------------------------------------

#define BAR() __builtin_amdgcn_s_barrier()

#define READ_A(BSEL, mh) do {                                                 \
    _Pragma("unroll") for (int ii = 0; ii < 4; ++ii)                          \
    _Pragma("unroll") for (int kk = 0; kk < 2; ++kk)                          \
        Af[ii][kk] = *(const bf16x8*)&As[BSEL][aoff[(mh)*4+ii] + ksw[kk]];    \
    } while (0)

#define READ_B(BSEL, j0) do {                                                 \
    _Pragma("unroll") for (int jj = 0; jj < 2; ++jj)                          \
    _Pragma("unroll") for (int kk = 0; kk < 2; ++kk)                          \
        Bf[(j0)+jj][kk] = *(const bf16x8*)&Bs[BSEL][bof[(j0)+jj] + ksw[kk]];  \
    } while (0)

#define MQ(i0, j0) do {                                                       \
    __builtin_amdgcn_s_setprio(1);                                            \
    _Pragma("unroll") for (int ii = 0; ii < 4; ++ii)                          \
    _Pragma("unroll") for (int jj = 0; jj < 2; ++jj)                          \
    _Pragma("unroll") for (int kk = 0; kk < 2; ++kk)                          \
        acc[(i0)+ii][(j0)+jj] =                                               \
            mfma16(Af[ii][kk], Bf[(j0)+jj][kk], acc[(i0)+ii][(j0)+jj]);       \
    __builtin_amdgcn_s_setprio(0);                                            \
    } while (0)

#define STAGE(BSEL, tt) do {                                                  \
    const size_t _k = (size_t)(tt) * 64;                                      \
    _Pragma("unroll") for (int c = 0; c < 4; ++c) {                           \
        gl2lds16(Ag + (size_t)c * 64 * lda + _k, &As[BSEL][c*4096 + w*512]);  \
        gl2lds16(Bg + (size_t)c * 64 * ldb + _k, &Bs[BSEL][c*4096 + w*512]);  \
    } } while (0)

// MODE: 0 = stage tile+2 & vmcnt(8); 1 = no stage, vmcnt(0); 2 = tail, none
#define TILE_ITER(BSEL, tt, MODE) do {                                        \
    READ_A(BSEL, 0); READ_B(BSEL, 0); BAR(); MQ(0, 0); BAR();                 \
    READ_B(BSEL, 2);                  BAR(); MQ(0, 2); BAR();                 \
    READ_A(BSEL, 1);                  BAR(); MQ(4, 2);                        \
    __builtin_amdgcn_sched_barrier(0); BAR();                                 \
    if (MODE == 0) STAGE(BSEL, (tt) + 2);                                     \
    BAR(); MQ(4, 0);                                                          \
    if (MODE == 0) asm volatile("s_waitcnt vmcnt(8)" ::: "memory");           \
    if (MODE == 1) asm volatile("s_waitcnt vmcnt(0)" ::: "memory");           \
    BAR(); } while (0)

template<typename OutT>
__global__ __launch_bounds__(512, 2) void gemm256(const bf16* __restrict__ A,
                                                  const bf16* __restrict__ B,
                                                  OutT* __restrict__ C,
                                                  int lda, int ldb, int ldc,
                                                  int K, int gx)
{
    __shared__ __align__(16) bf16 As[2][16384];   // 2 x 32 KB
    __shared__ __align__(16) bf16 Bs[2][16384];   // 2 x 32 KB  (128 KB total)

    const int tid  = threadIdx.x;
    const int w    = tid >> 6;        // wave 0..7
    const int l    = tid & 63;
    const int quad = l >> 4;
    const int ln   = l & 15;
    const int wm   = w >> 2;          // 0..1
    const int wn   = w & 3;           // 0..3

    // T1: chunked XCD swizzle (gridDim.x % 8 == 0 -> bijective)
    const int nwg = gridDim.x;
    const int bid = blockIdx.x;
    const int swz = (bid & 7) * (nwg >> 3) + (bid >> 3);
    const int bx  = swz % gx;
    const int by  = swz / gx;
    const size_t mbase = (size_t)by * 256;
    const size_t nbase = (size_t)bx * 256;

    // staging map: thread t -> row t>>3 (of 64-row pass), logical chunk
    // (t&7)^(row&7)  [pre-swizzled source so linear LDS dest = phys layout]
    const int srow   = tid >> 3;                  // 0..63
    const int schunk = (tid & 7) ^ (srow & 7);
    const bf16* Ag = A + (mbase + srow) * (size_t)lda + schunk * 8;
    const bf16* Bg = B + (nbase + srow) * (size_t)ldb + schunk * 8;

    // read-side element offsets (xor-swizzled k-chunk)
    const int xr = ln & 7;
    int aoff[8], bof[4], ksw[2];
#pragma unroll
    for (int i = 0; i < 8; ++i) aoff[i] = (wm * 128 + i * 16 + ln) * 64;
#pragma unroll
    for (int j = 0; j < 4; ++j) bof[j]  = (wn * 64  + j * 16 + ln) * 64;
#pragma unroll
    for (int kk = 0; kk < 2; ++kk) ksw[kk] = ((kk * 4 + quad) ^ xr) * 8;

    f32x4 acc[8][4];
#pragma unroll
    for (int i = 0; i < 8; ++i)
#pragma unroll
        for (int j = 0; j < 4; ++j) acc[i][j] = (f32x4){0.f, 0.f, 0.f, 0.f};

    bf16x8 Af[4][2];   // current A half (mh)
    bf16x8 Bf[4][2];   // all B frags for current K-tile

    // prologue: 2 K-tiles in flight
    STAGE(0, 0);
    STAGE(1, 1);
    asm volatile("s_waitcnt vmcnt(8)" ::: "memory");   // tile 0 landed
    BAR();

    const int NT = K >> 6;            // 32 for K=2048 (even, >=4)
    int t = 0;
#pragma unroll 1
    for (; t < NT - 2; t += 2) {
        TILE_ITER(0, t, 0);
        TILE_ITER(1, t + 1, 0);
    }
    TILE_ITER(0, NT - 2, 1);          // drain remaining loads (vmcnt 0)
    TILE_ITER(1, NT - 1, 2);          // last tile, nothing outstanding

    // C/D: col = ln, row = quad*4 + r  (m89/m91-verified)
#pragma unroll
    for (int i = 0; i < 8; ++i)
#pragma unroll
        for (int j = 0; j < 4; ++j)
#pragma unroll
            for (int r = 0; r < 4; ++r) {
                size_t row = mbase + wm * 128 + i * 16 + quad * 4 + r;
                size_t col = nbase + wn * 64 + j * 16 + ln;
                C[row * (size_t)ldc + col] = (OutT)acc[i][j][r];
            }
}

#undef BAR
#undef READ_A
#undef READ_B
#undef MQ
#undef STAGE
#undef TILE_ITER

// ---------------------------------------------------------------------------
// Attention over fused buffer, RoPE fused in. One workgroup per (b,h).
// Ks LDS holds roped K for phase 1, then is reused to hold P for phase 2.
// ---------------------------------------------------------------------------
__global__ __launch_bounds__(256) void attn_kernel(bf16* __restrict__ buf)
{
    __shared__ __align__(16) bf16 KP_lds[128 * 136];  // roped K, then P
    __shared__ __align__(16) bf16 Vt_lds[128 * 136];  // Vt[d][k] = V[k][d]

    const int bh = blockIdx.x;
    const int b  = bh >> 4;
    const int h  = bh & 15;
    const size_t baseQ = (size_t)b * SEQ * LDF + (size_t)h * D_HEAD;
    const size_t baseK = baseQ + KOFF;
    const size_t baseV = baseQ + VOFF;

    const int tid  = threadIdx.x;
    const int w    = tid >> 6;
    const int l    = tid & 63;
    const int quad = l >> 4;
    const int ln   = l & 15;

    // ---- stage roped K rows + V^T: thread -> row k=tid>>1, half d0=(tid&1)*64
    {
        int k  = tid >> 1;
        int d0 = (tid & 1) * 64;
        const bf16* kp = buf + baseK + (size_t)k * LDF + d0;
        const bf16* vp = buf + baseV + (size_t)k * LDF + d0;
        for (int c = 0; c < 8; ++c) {
            bf16x8 kv = *(const bf16x8*)(kp + c * 8);
            *(bf16x8*)&KP_lds[k * 136 + d0 + c * 8] = rope8(kv, k, d0 / 2 + c * 4);
            bf16x8 vv = *(const bf16x8*)(vp + c * 8);
            for (int j = 0; j < 8; ++j)
                Vt_lds[(d0 + c * 8 + j) * 136 + k] = vv[j];
        }
    }
    __syncthreads();

    const float rscale = 0.08838834764831845f;   // 1/sqrt(128)
    const float NEG    = -1e30f;

    // ---- phase 1: S = ropeQ @ ropeK^T for both strips, softmax in regs ----
    f32x4 acc2[2][8];
    for (int s = 0; s < 2; ++s)
        for (int nt = 0; nt < 8; ++nt) acc2[s][nt] = (f32x4){0.f, 0.f, 0.f, 0.f};

    for (int s = 0; s < 2; ++s) {
        const int q0 = w * 32 + s * 16;
        for (int kt = 0; kt < 4; ++kt) {
            bf16x8 qa = *(const bf16x8*)(buf + baseQ + (size_t)(q0 + ln) * LDF
                                           + kt * 32 + quad * 8);
            bf16x8 a = rope8(qa, q0 + ln, kt * 16 + quad * 4);
            for (int nt = 0; nt < 8; ++nt) {
                bf16x8 bb = *(const bf16x8*)&KP_lds[(nt * 16 + ln) * 136
                                                    + kt * 32 + quad * 8];
                acc2[s][nt] = mfma16(a, bb, acc2[s][nt]);
            }
        }

        float mx[4] = {NEG, NEG, NEG, NEG};
        for (int nt = 0; nt < 8; ++nt)
            for (int r = 0; r < 4; ++r) {
                int q = q0 + quad * 4 + r;
                int c = nt * 16 + ln;
                float v = acc2[s][nt][r] * rscale;
                v = (c <= q) ? v : NEG;
                acc2[s][nt][r] = v;
                mx[r] = fmaxf(mx[r], v);
            }
        for (int m = 1; m < 16; m <<= 1)
            for (int r = 0; r < 4; ++r)
                mx[r] = fmaxf(mx[r], __shfl_xor(mx[r], m));

        float sm[4] = {0.f, 0.f, 0.f, 0.f};
        for (int nt = 0; nt < 8; ++nt)
            for (int r = 0; r < 4; ++r) {
                float p = __expf(acc2[s][nt][r] - mx[r]);
                acc2[s][nt][r] = p;
                sm[r] += p;
            }
        for (int m = 1; m < 16; m <<= 1)
            for (int r = 0; r < 4; ++r)
                sm[r] += __shfl_xor(sm[r], m);

        for (int r = 0; r < 4; ++r) sm[r] = 1.0f / sm[r];
        for (int nt = 0; nt < 8; ++nt)
            for (int r = 0; r < 4; ++r)
                acc2[s][nt][r] *= sm[r];
    }

    __syncthreads();   // all K reads from KP_lds complete

    // ---- write P over the K region (own-wave rows only) ----
    for (int s = 0; s < 2; ++s)
        for (int nt = 0; nt < 8; ++nt)
            for (int r = 0; r < 4; ++r) {
                int q = w * 32 + s * 16 + quad * 4 + r;
                int c = nt * 16 + ln;
                KP_lds[q * 136 + c] = (bf16)acc2[s][nt][r];
            }

    // ---- phase 2: O = P @ V (P rows are own-wave; lgkmcnt orders w->r) ----
    f32x4 o[2][8];
    for (int s = 0; s < 2; ++s)
        for (int nt = 0; nt < 8; ++nt) o[s][nt] = (f32x4){0.f, 0.f, 0.f, 0.f};

    for (int kt = 0; kt < 4; ++kt) {
        bf16x8 a0 = *(const bf16x8*)&KP_lds[(w * 32 +      ln) * 136 + kt * 32 + quad * 8];
        bf16x8 a1 = *(const bf16x8*)&KP_lds[(w * 32 + 16 + ln) * 136 + kt * 32 + quad * 8];
        for (int nt = 0; nt < 8; ++nt) {
            bf16x8 bb = *(const bf16x8*)&Vt_lds[(nt * 16 + ln) * 136 + kt * 32 + quad * 8];
            o[0][nt] = mfma16(a0, bb, o[0][nt]);
            o[1][nt] = mfma16(a1, bb, o[1][nt]);
        }
    }

    for (int s = 0; s < 2; ++s)
        for (int nt = 0; nt < 8; ++nt)
            for (int r = 0; r < 4; ++r) {
                int q = w * 32 + s * 16 + quad * 4 + r;
                int d = nt * 16 + ln;
                buf[baseQ + (size_t)q * LDF + d] = (bf16)o[s][nt][r];
            }
}

// ---------------------------------------------------------------------------
extern "C" void kernel_launch(void* const* d_in, const int* in_sizes, int n_in,
                              void* d_out, int out_size, void* d_ws, size_t ws_size,
                              hipStream_t stream)
{
    const float* x  = (const float*)d_in[0];
    const float* Wq = (const float*)d_in[1];
    const float* Wk = (const float*)d_in[2];
    const float* Wv = (const float*)d_in[3];
    const float* Wo = (const float*)d_in[4];
    float* out = (float*)d_out;

    // ws layout (bf16 elems): QKV 100.7 MB | xb 33.6 MB (WoB reuses) | WB 25.2 MB
    bf16* QKV = (bf16*)d_ws;
    bf16* xb  = QKV + (size_t)BT * LDF;
    bf16* WB  = xb + (size_t)BT * D_MODEL;
    bf16* WoB = xb;                               // free after QKV GEMM

    const int n8x = BT * D_MODEL / 8;             // 2,097,152
    const int n8w = D_MODEL * D_MODEL / 8;        //   524,288 = 2^19

    cvt_kernel<<<(n8x + 255) / 256, 256, 0, stream>>>(x, xb, n8x);
    cvt_w3<<<(3 * n8w) / 256, 256, 0, stream>>>(Wq, Wk, Wv, WB);

    // fused QKV projection: [8192 x 6144] = xb @ WB^T  (768 blocks, %8==0)
    gemm256<bf16><<<dim3((LDF / 256) * (BT / 256)), 512, 0, stream>>>(
        xb, WB, QKV, D_MODEL, D_MODEL, LDF, D_MODEL, LDF / 256);

    cvt_kernel<<<(n8w + 255) / 256, 256, 0, stream>>>(Wo, WoB, n8w);

    // attention with fused RoPE; O in-place over Q columns
    attn_kernel<<<BATCH * N_HEADS, 256, 0, stream>>>(QKV);

    // output projection: out[8192 x 2048] = O @ Wo^T (fp32 out, 256 blocks)
    gemm256<float><<<dim3((D_MODEL / 256) * (BT / 256)), 512, 0, stream>>>(
        QKV, WoB, out, LDF, D_MODEL, D_MODEL, D_MODEL, D_MODEL / 256);
}

// Round 3
// 460.621 us; speedup vs baseline: 1.1155x; 1.0228x over previous
//
#include <hip/hip_runtime.h>
#include <hip/hip_bf16.h>
#include <math.h>

#define D_MODEL 2048
#define N_HEADS 16
#define D_HEAD  128
#define BATCH   64
#define SEQ     128
#define BT      (BATCH*SEQ)   // 8192 rows
#define LDF     6144          // fused QKV row stride
#define KOFF    2048
#define VOFF    4096

typedef __bf16 bf16;
typedef __attribute__((ext_vector_type(8))) __bf16 bf16x8;
typedef __attribute__((ext_vector_type(4))) float  f32x4;

__device__ __forceinline__ f32x4 mfma16(bf16x8 a, bf16x8 b, f32x4 c) {
    return __builtin_amdgcn_mfma_f32_16x16x32_bf16(a, b, c, 0, 0, 0);
}

__device__ __forceinline__ bf16x8 cvt8_f32(const float* p) {
    f32x4 lo = *(const f32x4*)p;
    f32x4 hi = *(const f32x4*)(p + 4);
    bf16x8 r;
    r[0] = (bf16)lo[0]; r[1] = (bf16)lo[1]; r[2] = (bf16)lo[2]; r[3] = (bf16)lo[3];
    r[4] = (bf16)hi[0]; r[5] = (bf16)hi[1]; r[6] = (bf16)hi[2]; r[7] = (bf16)hi[3];
    return r;
}

// async global->LDS, 16 B/lane; LDS dest = wave-uniform base + lane*16 (m104)
__device__ __forceinline__ void gl2lds16(const bf16* g, bf16* l) {
    __builtin_amdgcn_global_load_lds(
        (const __attribute__((address_space(1))) void*)g,
        (__attribute__((address_space(3))) void*)l, 16, 0, 0);
}

// rope 8 consecutive d-elements (4 even/odd pairs)
__device__ __forceinline__ bf16x8 rope8(bf16x8 v, int tpos, int pair0) {
    bf16x8 r;
    for (int m = 0; m < 4; ++m) {
        int i = pair0 + m;
        float theta = __expf((float)(2 * i) * (-9.210340371976184f / 128.0f));
        float ang   = (float)tpos * theta;
        float sn, cs;
        __sincosf(ang, &sn, &cs);
        float e = (float)v[2 * m], o = (float)v[2 * m + 1];
        r[2 * m]     = (bf16)(e * cs - o * sn);
        r[2 * m + 1] = (bf16)(e * sn + o * cs);
    }
    return r;
}

// ---------------------------------------------------------------------------
__global__ __launch_bounds__(256) void cvt_kernel(const float* __restrict__ src,
                                                  bf16* __restrict__ dst, int n8)
{
    int i = blockIdx.x * 256 + threadIdx.x;
    if (i < n8) *(bf16x8*)(dst + (size_t)i * 8) = cvt8_f32(src + (size_t)i * 8);
}

__global__ __launch_bounds__(256) void cvt_w3(const float* __restrict__ w0,
                                              const float* __restrict__ w1,
                                              const float* __restrict__ w2,
                                              bf16* __restrict__ dst)
{
    int i   = blockIdx.x * 256 + threadIdx.x;     // < 3*2^19
    int sel = i >> 19;
    int off = i & ((1 << 19) - 1);
    const float* s = (sel == 0) ? w0 : (sel == 1) ? w1 : w2;
    *(bf16x8*)(dst + (size_t)i * 8) = cvt8_f32(s + (size_t)off * 8);
}

// ---------------------------------------------------------------------------
// gemm256: C[M,N] = A[M,K] @ B[N,K]^T, bf16 in, OutT out.
// 256x256 tile, BK=64, 512 thr = 8 waves (2Mx4N), per-wave 128x64 output.
// m201-faithful phase skeleton, 4 phases/K-tile:
//   each phase: {ds_reads | 2x global_load_lds stage | SB0 | s_barrier |
//                asm lgkmcnt(0) | SB0 | setprio(1) 16 MFMA setprio(0) |
//                [P3: counted vmcnt] | SB0 | s_barrier}
// Stage spread (2 calls/phase, uniform): tile t's P0..P2 stage tile t+1
// chunks 2..7 into the OTHER buffer (legal: that buffer's reads finished at
// tile t-1's P2 end-bar); P3 stages tile t+2 chunks 0,1 into OWN buffer
// (legal: own reads finished at P2 end-bar). vmcnt(2) once per tile at P3
// end: waits tile t+1's 8 chunks (2 newest = t+2's chunks stay in flight;
// never vmcnt(0) in steady state). Explicit lgkmcnt(0)-AFTER-barrier +
// sched_barrier(0) fences pin wait placement (rule #18) so LDS service of
// one wave overlaps MFMA of earlier-served waves.
// ---------------------------------------------------------------------------

#define BAR() __builtin_amdgcn_s_barrier()
#define SB0() __builtin_amdgcn_sched_barrier(0)
#define WAIT_LGKM0() asm volatile("s_waitcnt lgkmcnt(0)" ::: "memory")

#define READ_A(BSEL, mh) do {                                                 \
    _Pragma("unroll") for (int ii = 0; ii < 4; ++ii)                          \
    _Pragma("unroll") for (int kk = 0; kk < 2; ++kk)                          \
        Af[ii][kk] = *(const bf16x8*)&As[BSEL][aoff[(mh)*4+ii] + ksw[kk]];    \
    } while (0)

#define READ_B(BSEL, j0) do {                                                 \
    _Pragma("unroll") for (int jj = 0; jj < 2; ++jj)                          \
    _Pragma("unroll") for (int kk = 0; kk < 2; ++kk)                          \
        Bf[(j0)+jj][kk] = *(const bf16x8*)&Bs[BSEL][bof[(j0)+jj] + ksw[kk]];  \
    } while (0)

#define MQ(i0, j0) do {                                                       \
    __builtin_amdgcn_s_setprio(1);                                            \
    _Pragma("unroll") for (int ii = 0; ii < 4; ++ii)                          \
    _Pragma("unroll") for (int jj = 0; jj < 2; ++jj)                          \
    _Pragma("unroll") for (int kk = 0; kk < 2; ++kk)                          \
        acc[(i0)+ii][(j0)+jj] =                                               \
            mfma16(Af[ii][kk], Bf[(j0)+jj][kk], acc[(i0)+ii][(j0)+jj]);       \
    __builtin_amdgcn_s_setprio(0);                                            \
    } while (0)

// stage one 64-row chunk (8 KB) of tile tt into buffer BSEL.
// c in 0..3 -> A rows c*64..; c in 4..7 -> B rows (c-4)*64..
#define STG1(BSEL, tt, c) do {                                                \
    if ((c) < 4)                                                              \
        gl2lds16(Ag + (size_t)(c) * 64 * lda + (size_t)(tt) * 64,             \
                 &As[BSEL][(c) * 4096 + w * 512]);                            \
    else                                                                      \
        gl2lds16(Bg + (size_t)((c) - 4) * 64 * ldb + (size_t)(tt) * 64,       \
                 &Bs[BSEL][((c) - 4) * 4096 + w * 512]);                      \
    } while (0)

// MODE: 0 = steady; 1 = pre-tail (stage t+1 only, vmcnt(0)); 2 = tail (none)
#define TILE_ITER(BSEL, OSEL, tt, MODE) do {                                  \
    /* ---- P0: A-half0 (8) + B01 (4) reads; stage t+1 c2,c3 ---- */          \
    READ_A(BSEL, 0); READ_B(BSEL, 0);                                         \
    if (MODE < 2) { STG1(OSEL, (tt) + 1, 2); STG1(OSEL, (tt) + 1, 3); }       \
    asm volatile("s_waitcnt lgkmcnt(8)" ::: "memory");                        \
    SB0(); BAR(); WAIT_LGKM0(); SB0();                                        \
    MQ(0, 0);                                                                 \
    SB0(); BAR();                                                             \
    /* ---- P1: B23 (4) reads; stage t+1 c4,c5 ---- */                        \
    READ_B(BSEL, 2);                                                          \
    if (MODE < 2) { STG1(OSEL, (tt) + 1, 4); STG1(OSEL, (tt) + 1, 5); }       \
    SB0(); BAR(); WAIT_LGKM0(); SB0();                                        \
    MQ(0, 2);                                                                 \
    SB0(); BAR();                                                             \
    /* ---- P2: A-half1 (8) reads; stage t+1 c6,c7 ---- */                    \
    READ_A(BSEL, 1);                                                          \
    if (MODE < 2) { STG1(OSEL, (tt) + 1, 6); STG1(OSEL, (tt) + 1, 7); }       \
    SB0(); BAR(); WAIT_LGKM0(); SB0();                                        \
    MQ(4, 2);                                                                 \
    SB0(); BAR();                                                             \
    /* ---- P3: no reads; stage t+2 c0,c1 into own buf; counted vmcnt ---- */ \
    if (MODE == 0) { STG1(BSEL, (tt) + 2, 0); STG1(BSEL, (tt) + 2, 1); }      \
    SB0(); BAR(); SB0();                                                      \
    MQ(4, 0);                                                                 \
    if (MODE == 0) asm volatile("s_waitcnt vmcnt(2)" ::: "memory");           \
    if (MODE == 1) asm volatile("s_waitcnt vmcnt(0)" ::: "memory");           \
    SB0(); BAR(); } while (0)

template<typename OutT>
__global__ __launch_bounds__(512, 2) void gemm256(const bf16* __restrict__ A,
                                                  const bf16* __restrict__ B,
                                                  OutT* __restrict__ C,
                                                  int lda, int ldb, int ldc,
                                                  int K, int gx)
{
    __shared__ __align__(16) bf16 As[2][16384];   // 2 x 32 KB
    __shared__ __align__(16) bf16 Bs[2][16384];   // 2 x 32 KB  (128 KB total)

    const int tid  = threadIdx.x;
    const int w    = tid >> 6;        // wave 0..7
    const int l    = tid & 63;
    const int quad = l >> 4;
    const int ln   = l & 15;
    const int wm   = w >> 2;          // 0..1
    const int wn   = w & 3;           // 0..3

    // T1: chunked XCD swizzle (gridDim.x % 8 == 0 -> bijective)
    const int nwg = gridDim.x;
    const int bid = blockIdx.x;
    const int swz = (bid & 7) * (nwg >> 3) + (bid >> 3);
    const int bx  = swz % gx;
    const int by  = swz / gx;
    const size_t mbase = (size_t)by * 256;
    const size_t nbase = (size_t)bx * 256;

    // staging map: thread t -> row t>>3 (of 64-row chunk), logical 8-elem
    // chunk (t&7)^(row&7)  [pre-swizzled source; linear LDS dest = m104-safe]
    const int srow   = tid >> 3;                  // 0..63
    const int schunk = (tid & 7) ^ (srow & 7);
    const bf16* Ag = A + (mbase + srow) * (size_t)lda + schunk * 8;
    const bf16* Bg = B + (nbase + srow) * (size_t)ldb + schunk * 8;

    // read-side element offsets (xor-swizzled k-chunk)
    const int xr = ln & 7;
    int aoff[8], bof[4], ksw[2];
#pragma unroll
    for (int i = 0; i < 8; ++i) aoff[i] = (wm * 128 + i * 16 + ln) * 64;
#pragma unroll
    for (int j = 0; j < 4; ++j) bof[j]  = (wn * 64  + j * 16 + ln) * 64;
#pragma unroll
    for (int kk = 0; kk < 2; ++kk) ksw[kk] = ((kk * 4 + quad) ^ xr) * 8;

    f32x4 acc[8][4];
#pragma unroll
    for (int i = 0; i < 8; ++i)
#pragma unroll
        for (int j = 0; j < 4; ++j) acc[i][j] = (f32x4){0.f, 0.f, 0.f, 0.f};

    bf16x8 Af[4][2];   // current A half
    bf16x8 Bf[4][2];   // all B frags for current K-tile

    // prologue: tile0 full burst + tile1 chunks 0,1  (10 calls in flight)
    STG1(0, 0, 0); STG1(0, 0, 1); STG1(0, 0, 2); STG1(0, 0, 3);
    STG1(0, 0, 4); STG1(0, 0, 5); STG1(0, 0, 6); STG1(0, 0, 7);
    STG1(1, 1, 0); STG1(1, 1, 1);
    asm volatile("s_waitcnt vmcnt(2)" ::: "memory");   // tile0 landed
    BAR();

    const int NT = K >> 6;            // 32 for K=2048 (even, >=4)
    int t = 0;
#pragma unroll 1
    for (; t < NT - 2; t += 2) {
        TILE_ITER(0, 1, t, 0);
        TILE_ITER(1, 0, t + 1, 0);
    }
    TILE_ITER(0, 1, NT - 2, 1);       // stages tile NT-1 tail chunks, vmcnt(0)
    TILE_ITER(1, 0, NT - 1, 2);       // last tile, nothing outstanding

    // C/D: col = ln, row = quad*4 + r  (m89/m91-verified)
#pragma unroll
    for (int i = 0; i < 8; ++i)
#pragma unroll
        for (int j = 0; j < 4; ++j)
#pragma unroll
            for (int r = 0; r < 4; ++r) {
                size_t row = mbase + wm * 128 + i * 16 + quad * 4 + r;
                size_t col = nbase + wn * 64 + j * 16 + ln;
                C[row * (size_t)ldc + col] = (OutT)acc[i][j][r];
            }
}

#undef BAR
#undef SB0
#undef WAIT_LGKM0
#undef READ_A
#undef READ_B
#undef MQ
#undef STG1
#undef TILE_ITER

// ---------------------------------------------------------------------------
// Attention over fused buffer, RoPE fused in. One workgroup per (b,h).
// ---------------------------------------------------------------------------
__global__ __launch_bounds__(256) void attn_kernel(bf16* __restrict__ buf)
{
    __shared__ __align__(16) bf16 KP_lds[128 * 136];  // roped K, then P
    __shared__ __align__(16) bf16 Vt_lds[128 * 136];  // Vt[d][k] = V[k][d]

    const int bh = blockIdx.x;
    const int b  = bh >> 4;
    const int h  = bh & 15;
    const size_t baseQ = (size_t)b * SEQ * LDF + (size_t)h * D_HEAD;
    const size_t baseK = baseQ + KOFF;
    const size_t baseV = baseQ + VOFF;

    const int tid  = threadIdx.x;
    const int w    = tid >> 6;
    const int l    = tid & 63;
    const int quad = l >> 4;
    const int ln   = l & 15;

    // ---- stage roped K rows + V^T: thread -> row k=tid>>1, half d0=(tid&1)*64
    {
        int k  = tid >> 1;
        int d0 = (tid & 1) * 64;
        const bf16* kp = buf + baseK + (size_t)k * LDF + d0;
        const bf16* vp = buf + baseV + (size_t)k * LDF + d0;
        for (int c = 0; c < 8; ++c) {
            bf16x8 kv = *(const bf16x8*)(kp + c * 8);
            *(bf16x8*)&KP_lds[k * 136 + d0 + c * 8] = rope8(kv, k, d0 / 2 + c * 4);
            bf16x8 vv = *(const bf16x8*)(vp + c * 8);
            for (int j = 0; j < 8; ++j)
                Vt_lds[(d0 + c * 8 + j) * 136 + k] = vv[j];
        }
    }
    __syncthreads();

    const float rscale = 0.08838834764831845f;   // 1/sqrt(128)
    const float NEG    = -1e30f;

    // ---- phase 1: S = ropeQ @ ropeK^T for both strips, softmax in regs ----
    f32x4 acc2[2][8];
    for (int s = 0; s < 2; ++s)
        for (int nt = 0; nt < 8; ++nt) acc2[s][nt] = (f32x4){0.f, 0.f, 0.f, 0.f};

    for (int s = 0; s < 2; ++s) {
        const int q0 = w * 32 + s * 16;
        for (int kt = 0; kt < 4; ++kt) {
            bf16x8 qa = *(const bf16x8*)(buf + baseQ + (size_t)(q0 + ln) * LDF
                                           + kt * 32 + quad * 8);
            bf16x8 a = rope8(qa, q0 + ln, kt * 16 + quad * 4);
            for (int nt = 0; nt < 8; ++nt) {
                bf16x8 bb = *(const bf16x8*)&KP_lds[(nt * 16 + ln) * 136
                                                    + kt * 32 + quad * 8];
                acc2[s][nt] = mfma16(a, bb, acc2[s][nt]);
            }
        }

        float mx[4] = {NEG, NEG, NEG, NEG};
        for (int nt = 0; nt < 8; ++nt)
            for (int r = 0; r < 4; ++r) {
                int q = q0 + quad * 4 + r;
                int c = nt * 16 + ln;
                float v = acc2[s][nt][r] * rscale;
                v = (c <= q) ? v : NEG;
                acc2[s][nt][r] = v;
                mx[r] = fmaxf(mx[r], v);
            }
        for (int m = 1; m < 16; m <<= 1)
            for (int r = 0; r < 4; ++r)
                mx[r] = fmaxf(mx[r], __shfl_xor(mx[r], m));

        float sm[4] = {0.f, 0.f, 0.f, 0.f};
        for (int nt = 0; nt < 8; ++nt)
            for (int r = 0; r < 4; ++r) {
                float p = __expf(acc2[s][nt][r] - mx[r]);
                acc2[s][nt][r] = p;
                sm[r] += p;
            }
        for (int m = 1; m < 16; m <<= 1)
            for (int r = 0; r < 4; ++r)
                sm[r] += __shfl_xor(sm[r], m);

        for (int r = 0; r < 4; ++r) sm[r] = 1.0f / sm[r];
        for (int nt = 0; nt < 8; ++nt)
            for (int r = 0; r < 4; ++r)
                acc2[s][nt][r] *= sm[r];
    }

    __syncthreads();   // all K reads from KP_lds complete

    // ---- write P over the K region (own-wave rows only) ----
    for (int s = 0; s < 2; ++s)
        for (int nt = 0; nt < 8; ++nt)
            for (int r = 0; r < 4; ++r) {
                int q = w * 32 + s * 16 + quad * 4 + r;
                int c = nt * 16 + ln;
                KP_lds[q * 136 + c] = (bf16)acc2[s][nt][r];
            }

    // ---- phase 2: O = P @ V ----
    f32x4 o[2][8];
    for (int s = 0; s < 2; ++s)
        for (int nt = 0; nt < 8; ++nt) o[s][nt] = (f32x4){0.f, 0.f, 0.f, 0.f};

    for (int kt = 0; kt < 4; ++kt) {
        bf16x8 a0 = *(const bf16x8*)&KP_lds[(w * 32 +      ln) * 136 + kt * 32 + quad * 8];
        bf16x8 a1 = *(const bf16x8*)&KP_lds[(w * 32 + 16 + ln) * 136 + kt * 32 + quad * 8];
        for (int nt = 0; nt < 8; ++nt) {
            bf16x8 bb = *(const bf16x8*)&Vt_lds[(nt * 16 + ln) * 136 + kt * 32 + quad * 8];
            o[0][nt] = mfma16(a0, bb, o[0][nt]);
            o[1][nt] = mfma16(a1, bb, o[1][nt]);
        }
    }

    for (int s = 0; s < 2; ++s)
        for (int nt = 0; nt < 8; ++nt)
            for (int r = 0; r < 4; ++r) {
                int q = w * 32 + s * 16 + quad * 4 + r;
                int d = nt * 16 + ln;
                buf[baseQ + (size_t)q * LDF + d] = (bf16)o[s][nt][r];
            }
}

// ---------------------------------------------------------------------------
extern "C" void kernel_launch(void* const* d_in, const int* in_sizes, int n_in,
                              void* d_out, int out_size, void* d_ws, size_t ws_size,
                              hipStream_t stream)
{
    const float* x  = (const float*)d_in[0];
    const float* Wq = (const float*)d_in[1];
    const float* Wk = (const float*)d_in[2];
    const float* Wv = (const float*)d_in[3];
    const float* Wo = (const float*)d_in[4];
    float* out = (float*)d_out;

    // ws layout (bf16 elems): QKV 100.7 MB | xb 33.6 MB (WoB reuses) | WB 25.2 MB
    bf16* QKV = (bf16*)d_ws;
    bf16* xb  = QKV + (size_t)BT * LDF;
    bf16* WB  = xb + (size_t)BT * D_MODEL;
    bf16* WoB = xb;                               // free after QKV GEMM

    const int n8x = BT * D_MODEL / 8;             // 2,097,152
    const int n8w = D_MODEL * D_MODEL / 8;        //   524,288 = 2^19

    cvt_kernel<<<(n8x + 255) / 256, 256, 0, stream>>>(x, xb, n8x);
    cvt_w3<<<(3 * n8w) / 256, 256, 0, stream>>>(Wq, Wk, Wv, WB);

    // fused QKV projection: [8192 x 6144] = xb @ WB^T  (768 blocks, %8==0)
    gemm256<bf16><<<dim3((LDF / 256) * (BT / 256)), 512, 0, stream>>>(
        xb, WB, QKV, D_MODEL, D_MODEL, LDF, D_MODEL, LDF / 256);

    cvt_kernel<<<(n8w + 255) / 256, 256, 0, stream>>>(Wo, WoB, n8w);

    // attention with fused RoPE; O in-place over Q columns
    attn_kernel<<<BATCH * N_HEADS, 256, 0, stream>>>(QKV);

    // output projection: out[8192 x 2048] = O @ Wo^T (fp32 out, 256 blocks)
    gemm256<float><<<dim3((D_MODEL / 256) * (BT / 256)), 512, 0, stream>>>(
        QKV, WoB, out, LDF, D_MODEL, D_MODEL, D_MODEL, D_MODEL / 256);
}